// Round 7
// baseline (395.168 us; speedup 1.0000x reference)
//
#include <hip/hip_runtime.h>
#include <hip/hip_fp16.h>

#define NEG_SLOPE 0.2f
#define NPB 128            // nodes per bucket (dst >> 7); requires N <= 131072
#define MAXB 1024          // max buckets

__device__ __forceinline__ unsigned pk2(float a, float b) {
    __half2 h = __floats2half2_rn(a, b);
    return *(unsigned*)&h;
}
__device__ __forceinline__ float exh(unsigned u, int hi) {
    __half2 h = *(__half2*)&u;
    return hi ? __high2float(h) : __low2float(h);
}

// ===========================================================================
// P0: bucket edge counts via block-local LDS histogram
// ===========================================================================
__global__ void p0_count(const int* __restrict__ dst, int* __restrict__ bcnt,
                         int E, int nbuck)
{
    __shared__ int hist[MAXB];
    for (int b = threadIdx.x; b < nbuck; b += blockDim.x) hist[b] = 0;
    __syncthreads();
    int tile = blockIdx.x * 4096;
    int cnt = min(4096, E - tile);
    for (int k = threadIdx.x; k < cnt; k += blockDim.x)
        atomicAdd(&hist[dst[tile + k] >> 7], 1);
    __syncthreads();
    for (int b = threadIdx.x; b < nbuck; b += blockDim.x) {
        int v = hist[b];
        if (v) atomicAdd(&bcnt[b], v);
    }
}

// ===========================================================================
// P1: exclusive scan of bucket counts (single block)
// ===========================================================================
__global__ void p1_scan(const int* __restrict__ bcnt, int* __restrict__ bbase,
                        int* __restrict__ bcur, int nbuck)
{
    __shared__ int sm[MAXB];
    int t = threadIdx.x;
    int v = (t < nbuck) ? bcnt[t] : 0;
    sm[t] = v;
    __syncthreads();
    for (int off = 1; off < MAXB; off <<= 1) {
        int x = (t >= off) ? sm[t - off] : 0;
        __syncthreads();
        sm[t] += x;
        __syncthreads();
    }
    if (t < nbuck) { int e = sm[t] - v; bbase[t] = e; bcur[t] = e; }
}

// ===========================================================================
// P2: scatter edges into bucket regions, packed (src<<7)|(dst&127)
// ===========================================================================
__global__ void p2_scatter(const int* __restrict__ src, const int* __restrict__ dst,
                           int* __restrict__ bcur, int* __restrict__ ebuf,
                           int E, int nbuck)
{
    __shared__ int hist[MAXB];
    __shared__ int base[MAXB];
    __shared__ int pk[4096];
    __shared__ unsigned short pb[4096];
    for (int b = threadIdx.x; b < nbuck; b += blockDim.x) hist[b] = 0;
    __syncthreads();
    int tile = blockIdx.x * 4096;
    int cnt = min(4096, E - tile);
    for (int k = threadIdx.x; k < cnt; k += blockDim.x) {
        int i = tile + k;
        int d = dst[i];
        int b = d >> 7;
        pk[k] = (src[i] << 7) | (d & 127);
        pb[k] = (unsigned short)b;
        atomicAdd(&hist[b], 1);
    }
    __syncthreads();
    for (int b = threadIdx.x; b < nbuck; b += blockDim.x) {
        int v = hist[b];
        base[b] = v ? atomicAdd(&bcur[b], v) : 0;
        hist[b] = 0;                      // reuse as rank cursor
    }
    __syncthreads();
    for (int k = threadIdx.x; k < cnt; k += blockDim.x) {
        int b = pb[k];
        int r = atomicAdd(&hist[b], 1);
        ebuf[base[b] + r] = pk[k];
    }
}

// ===========================================================================
// P3: within-bucket counting sort -> exact per-node CSR
// ===========================================================================
__global__ void p3_sort(const int* __restrict__ bbase, const int* __restrict__ bcnt,
                        const int* __restrict__ ebuf,
                        int* __restrict__ rowp, int* __restrict__ deg,
                        int* __restrict__ esrc, int N)
{
    __shared__ int hist[NPB];
    __shared__ int ls[NPB];
    int b = blockIdx.x;
    int n0 = b * NPB;
    if (threadIdx.x < NPB) hist[threadIdx.x] = 0;
    __syncthreads();
    int es = bbase[b], ec = bcnt[b];
    for (int k = threadIdx.x; k < ec; k += blockDim.x)
        atomicAdd(&hist[ebuf[es + k] & 127], 1);
    __syncthreads();
    if (threadIdx.x < NPB) ls[threadIdx.x] = hist[threadIdx.x];
    __syncthreads();
    for (int off = 1; off < NPB; off <<= 1) {
        int v = 0;
        if (threadIdx.x < NPB && threadIdx.x >= off) v = ls[threadIdx.x - off];
        __syncthreads();
        if (threadIdx.x < NPB) ls[threadIdx.x] += v;
        __syncthreads();
    }
    if (threadIdx.x < NPB) {
        int ex = ls[threadIdx.x] - hist[threadIdx.x];   // exclusive
        ls[threadIdx.x] = ex;
        int n = n0 + threadIdx.x;
        if (n < N) { rowp[n] = es + ex; deg[n] = hist[threadIdx.x]; }
        hist[threadIdx.x] = 0;            // reuse as cursor
    }
    __syncthreads();
    for (int k = threadIdx.x; k < ec; k += blockDim.x) {
        int v = ebuf[es + k];
        int ln = v & 127;
        int r = atomicAdd(&hist[ln], 1);
        esrc[es + ls[ln] + r] = v >> 7;
    }
}

// ===========================================================================
// Fold attention vectors through layer weights (240 outputs)
// ===========================================================================
__global__ void k_fold(const float* __restrict__ W1,
                       const float* __restrict__ s1, const float* __restrict__ d1,
                       const float* __restrict__ W2,
                       const float* __restrict__ s2, const float* __restrict__ d2,
                       float* __restrict__ fold)
{
    int t = threadIdx.x;
    if (t < 24) {
        int h = t / 6, k = t % 6;
        float v = 0.f;
        for (int c = 0; c < 6; ++c) v += W1[k * 24 + h * 6 + c] * s1[h * 6 + c];
        fold[t] = v;
    } else if (t < 48) {
        int u = t - 24, h = u / 6, k = u % 6;
        float v = 0.f;
        for (int c = 0; c < 6; ++c) v += W1[k * 24 + h * 6 + c] * d1[h * 6 + c];
        fold[t] = v;
    } else if (t < 144) {
        int u = t - 48, h = u / 24, k = u % 24;
        float v = 0.f;
        for (int c = 0; c < 30; ++c) v += W2[k * 120 + h * 30 + c] * s2[h * 30 + c];
        fold[t] = v;
    } else if (t < 240) {
        int u = t - 144, h = u / 24, k = u % 24;
        float v = 0.f;
        for (int c = 0; c < 30; ++c) v += W2[k * 120 + h * 30 + c] * d2[h * 30 + c];
        fold[t] = v;
    }
}

// ===========================================================================
// K1: compute layer-1 logits; write row1[n] = [as1 4xfp16 | x 6xfp32] (32B)
// and ad1 (fp32).
// ===========================================================================
__global__ void k1_row(const float* __restrict__ x,
                       const float* __restrict__ fold,
                       float* __restrict__ row1, float* __restrict__ ad1, int N)
{
    int n = blockIdx.x * blockDim.x + threadIdx.x;
    if (n >= N) return;
    float xv[6];
#pragma unroll
    for (int k = 0; k < 6; ++k) xv[k] = x[n * 6 + k];
    float as[4], ad[4];
#pragma unroll
    for (int h = 0; h < 4; ++h) {
        float a = 0.f, d = 0.f;
#pragma unroll
        for (int k = 0; k < 6; ++k) {
            a += xv[k] * fold[h * 6 + k];
            d += xv[k] * fold[24 + h * 6 + k];
        }
        as[h] = a; ad[h] = d;
        ad1[n * 4 + h] = d;
    }
    uint4 u0, u1;
    u0.x = pk2(as[0], as[1]);
    u0.y = pk2(as[2], as[3]);
    u0.z = __float_as_uint(xv[0]);
    u0.w = __float_as_uint(xv[1]);
    u1.x = __float_as_uint(xv[2]);
    u1.y = __float_as_uint(xv[3]);
    u1.z = __float_as_uint(xv[4]);
    u1.w = __float_as_uint(xv[5]);
    uint4* rp = (uint4*)row1 + (size_t)n * 2;
    rp[0] = u0; rp[1] = u1;
}

// ===========================================================================
// Gather layer 1 (8 threads/node: h = o&3, half = o>>2). Random reads hit a
// single 3.2 MB row1 region (L2-resident). Epilogue: project W1_h, compute
// fused layer-2 logits, write rowA/rowB ([as2 fp16 | g ch fp16], 32B) + ad2.
// ===========================================================================
__global__ void k_gather1(const int* __restrict__ rowp, const int* __restrict__ deg,
                          const int* __restrict__ esrc,
                          const float* __restrict__ row1,
                          const float* __restrict__ ad1,
                          const float* __restrict__ W1, const float* __restrict__ b1,
                          const float* __restrict__ fold,
                          float* __restrict__ rowA, float* __restrict__ rowB,
                          float* __restrict__ ad2, int N)
{
    int t = blockIdx.x * blockDim.x + threadIdx.x;
    int n = t >> 3;
    if (n >= N) return;
    int o = t & 7;
    int h = o & 3;
    int half = o >> 2;
    float adn = ad1[n * 4 + h];
    const uint4* R = (const uint4*)row1;

    float acc[6] = {0.f, 0.f, 0.f, 0.f, 0.f, 0.f};
    float den = 0.f;
    if (half == 0) {   // self loop
        uint4 u0 = R[(size_t)n * 2], u1 = R[(size_t)n * 2 + 1];
        float asn = exh((h < 2) ? u0.x : u0.y, h & 1);
        float e0 = asn + adn;
        e0 = e0 > 0.f ? e0 : NEG_SLOPE * e0;
        float w = expf(e0);
        den = w;
        acc[0] = w * __uint_as_float(u0.z);
        acc[1] = w * __uint_as_float(u0.w);
        acc[2] = w * __uint_as_float(u1.x);
        acc[3] = w * __uint_as_float(u1.y);
        acc[4] = w * __uint_as_float(u1.z);
        acc[5] = w * __uint_as_float(u1.w);
    }
    int start = rowp[n], cnt = deg[n];
    for (int k = half; k < cnt; k += 2) {
        int s = esrc[start + k];
        uint4 u0 = R[(size_t)s * 2], u1 = R[(size_t)s * 2 + 1];
        float as = exh((h < 2) ? u0.x : u0.y, h & 1);
        float e = as + adn;
        e = e > 0.f ? e : NEG_SLOPE * e;
        float w = expf(e);
        den += w;
        acc[0] += w * __uint_as_float(u0.z);
        acc[1] += w * __uint_as_float(u0.w);
        acc[2] += w * __uint_as_float(u1.x);
        acc[3] += w * __uint_as_float(u1.y);
        acc[4] += w * __uint_as_float(u1.z);
        acc[5] += w * __uint_as_float(u1.w);
    }
    // merge halves
    den += __shfl_xor(den, 4);
#pragma unroll
    for (int k = 0; k < 6; ++k) acc[k] += __shfl_xor(acc[k], 4);

    float inv = 1.f / (den + 1e-16f);
    float m[6];
#pragma unroll
    for (int k = 0; k < 6; ++k) m[k] = acc[k] * inv;

    // project W1_h: gc[c] = relu(m . W1[:, h*6+c] + b1)
    float gc[6];
#pragma unroll
    for (int c = 0; c < 6; ++c) {
        float v = b1[h * 6 + c];
#pragma unroll
        for (int k = 0; k < 6; ++k) v += m[k] * W1[k * 24 + h * 6 + c];
        gc[c] = v > 0.f ? v : 0.f;
    }
    // fused layer-2 logits (partial over this lane's 6 channels, all 4 heads)
    float pas[4], pad[4];
#pragma unroll
    for (int hh = 0; hh < 4; ++hh) {
        float a = 0.f, d = 0.f;
#pragma unroll
        for (int c = 0; c < 6; ++c) {
            a += gc[c] * fold[48 + hh * 24 + h * 6 + c];
            d += gc[c] * fold[144 + hh * 24 + h * 6 + c];
        }
        pas[hh] = a; pad[hh] = d;
    }
#pragma unroll
    for (int hh = 0; hh < 4; ++hh) {
        pas[hh] += __shfl_xor(pas[hh], 1);
        pas[hh] += __shfl_xor(pas[hh], 2);
        pad[hh] += __shfl_xor(pad[hh], 1);
        pad[hh] += __shfl_xor(pad[hh], 2);
    }
    if (half == 0) {
        unsigned* rp = (unsigned*)((h < 2) ? rowA : rowB) + (size_t)n * 8;
        if ((h & 1) == 0) {
            rp[0] = pk2(pas[0], pas[1]);
            rp[1] = pk2(pas[2], pas[3]);
        }
        int gb = 2 + (h & 1) * 3;
        rp[gb + 0] = pk2(gc[0], gc[1]);
        rp[gb + 1] = pk2(gc[2], gc[3]);
        rp[gb + 2] = pk2(gc[4], gc[5]);
        ad2[n * 4 + h] = pad[h];
    }
}

// ===========================================================================
// Gather layer 2, PASS A: channels 0-11 from rowA (3.2 MB, L2-resident).
// Writes head-summed partial projection zA[N,30].
// ===========================================================================
__global__ void k_g2a(const int* __restrict__ rowp, const int* __restrict__ deg,
                      const int* __restrict__ esrc,
                      const float* __restrict__ rowA, const float* __restrict__ ad2,
                      const float* __restrict__ W2,
                      float* __restrict__ zA, int N)
{
    int t = blockIdx.x * blockDim.x + threadIdx.x;
    int n = t >> 3;
    if (n >= N) return;
    int o = t & 7;
    int h = o & 3;
    int half = o >> 2;
    float adn = ad2[n * 4 + h];
    const uint4* R = (const uint4*)rowA;

    float acc[12];
#pragma unroll
    for (int k = 0; k < 12; ++k) acc[k] = 0.f;
    float den = 0.f;

    if (half == 0) {   // self loop
        uint4 u0 = R[(size_t)n * 2], u1 = R[(size_t)n * 2 + 1];
        float as = exh((h < 2) ? u0.x : u0.y, h & 1);
        float e = as + adn; e = e > 0.f ? e : NEG_SLOPE * e;
        float w = expf(e);
        den = w;
        float2 g0 = __half22float2(*(__half2*)&u0.z);
        float2 g1 = __half22float2(*(__half2*)&u0.w);
        float2 g2 = __half22float2(*(__half2*)&u1.x);
        float2 g3 = __half22float2(*(__half2*)&u1.y);
        float2 g4 = __half22float2(*(__half2*)&u1.z);
        float2 g5 = __half22float2(*(__half2*)&u1.w);
        acc[0]=w*g0.x; acc[1]=w*g0.y; acc[2]=w*g1.x; acc[3]=w*g1.y;
        acc[4]=w*g2.x; acc[5]=w*g2.y; acc[6]=w*g3.x; acc[7]=w*g3.y;
        acc[8]=w*g4.x; acc[9]=w*g4.y; acc[10]=w*g5.x; acc[11]=w*g5.y;
    }
    int start = rowp[n], cnt = deg[n];
    for (int k = half; k < cnt; k += 2) {
        int s = esrc[start + k];
        uint4 u0 = R[(size_t)s * 2], u1 = R[(size_t)s * 2 + 1];
        float as = exh((h < 2) ? u0.x : u0.y, h & 1);
        float e = as + adn; e = e > 0.f ? e : NEG_SLOPE * e;
        float w = expf(e);
        den += w;
        float2 g0 = __half22float2(*(__half2*)&u0.z);
        float2 g1 = __half22float2(*(__half2*)&u0.w);
        float2 g2 = __half22float2(*(__half2*)&u1.x);
        float2 g3 = __half22float2(*(__half2*)&u1.y);
        float2 g4 = __half22float2(*(__half2*)&u1.z);
        float2 g5 = __half22float2(*(__half2*)&u1.w);
        acc[0]+=w*g0.x; acc[1]+=w*g0.y; acc[2]+=w*g1.x; acc[3]+=w*g1.y;
        acc[4]+=w*g2.x; acc[5]+=w*g2.y; acc[6]+=w*g3.x; acc[7]+=w*g3.y;
        acc[8]+=w*g4.x; acc[9]+=w*g4.y; acc[10]+=w*g5.x; acc[11]+=w*g5.y;
    }
    den += __shfl_xor(den, 4);
#pragma unroll
    for (int k = 0; k < 12; ++k) acc[k] += __shfl_xor(acc[k], 4);
    float inv = 1.f / (den + 1e-16f);
#pragma unroll
    for (int k = 0; k < 12; ++k) acc[k] *= inv;

    // partial projection: channels [half*15, half*15+15), K rows 0-11
    float vv[15];
#pragma unroll
    for (int cc = 0; cc < 15; ++cc) {
        int c = half * 15 + cc;
        float v = 0.f;
#pragma unroll
        for (int k = 0; k < 12; ++k) v += acc[k] * W2[k * 120 + h * 30 + c];
        v += __shfl_xor(v, 1);
        v += __shfl_xor(v, 2);
        vv[cc] = v;
    }
    if (h == 0) {
#pragma unroll
        for (int cc = 0; cc < 15; ++cc)
            zA[(size_t)n * 30 + half * 15 + cc] = vv[cc];
    }
}

// ===========================================================================
// Gather layer 2, PASS B: channels 12-23 from rowB + zA -> full epilogue
// (head mean + b2 + relu + MLP 30->15->2).
// ===========================================================================
__global__ void k_g2b(const int* __restrict__ rowp, const int* __restrict__ deg,
                      const int* __restrict__ esrc,
                      const float* __restrict__ rowB, const float* __restrict__ ad2,
                      const float* __restrict__ W2, const float* __restrict__ zA,
                      const float* __restrict__ b2,
                      const float* __restrict__ fw1, const float* __restrict__ fb1,
                      const float* __restrict__ fw2, const float* __restrict__ fb2,
                      float* __restrict__ out, int N)
{
    int t = blockIdx.x * blockDim.x + threadIdx.x;
    int n = t >> 3;
    if (n >= N) return;
    int o = t & 7;
    int h = o & 3;
    int half = o >> 2;
    float adn = ad2[n * 4 + h];
    const uint4* R = (const uint4*)rowB;

    float acc[12];
#pragma unroll
    for (int k = 0; k < 12; ++k) acc[k] = 0.f;
    float den = 0.f;

    if (half == 0) {   // self loop
        uint4 u0 = R[(size_t)n * 2], u1 = R[(size_t)n * 2 + 1];
        float as = exh((h < 2) ? u0.x : u0.y, h & 1);
        float e = as + adn; e = e > 0.f ? e : NEG_SLOPE * e;
        float w = expf(e);
        den = w;
        float2 g0 = __half22float2(*(__half2*)&u0.z);
        float2 g1 = __half22float2(*(__half2*)&u0.w);
        float2 g2 = __half22float2(*(__half2*)&u1.x);
        float2 g3 = __half22float2(*(__half2*)&u1.y);
        float2 g4 = __half22float2(*(__half2*)&u1.z);
        float2 g5 = __half22float2(*(__half2*)&u1.w);
        acc[0]=w*g0.x; acc[1]=w*g0.y; acc[2]=w*g1.x; acc[3]=w*g1.y;
        acc[4]=w*g2.x; acc[5]=w*g2.y; acc[6]=w*g3.x; acc[7]=w*g3.y;
        acc[8]=w*g4.x; acc[9]=w*g4.y; acc[10]=w*g5.x; acc[11]=w*g5.y;
    }
    int start = rowp[n], cnt = deg[n];
    for (int k = half; k < cnt; k += 2) {
        int s = esrc[start + k];
        uint4 u0 = R[(size_t)s * 2], u1 = R[(size_t)s * 2 + 1];
        float as = exh((h < 2) ? u0.x : u0.y, h & 1);
        float e = as + adn; e = e > 0.f ? e : NEG_SLOPE * e;
        float w = expf(e);
        den += w;
        float2 g0 = __half22float2(*(__half2*)&u0.z);
        float2 g1 = __half22float2(*(__half2*)&u0.w);
        float2 g2 = __half22float2(*(__half2*)&u1.x);
        float2 g3 = __half22float2(*(__half2*)&u1.y);
        float2 g4 = __half22float2(*(__half2*)&u1.z);
        float2 g5 = __half22float2(*(__half2*)&u1.w);
        acc[0]+=w*g0.x; acc[1]+=w*g0.y; acc[2]+=w*g1.x; acc[3]+=w*g1.y;
        acc[4]+=w*g2.x; acc[5]+=w*g2.y; acc[6]+=w*g3.x; acc[7]+=w*g3.y;
        acc[8]+=w*g4.x; acc[9]+=w*g4.y; acc[10]+=w*g5.x; acc[11]+=w*g5.y;
    }
    den += __shfl_xor(den, 4);
#pragma unroll
    for (int k = 0; k < 12; ++k) acc[k] += __shfl_xor(acc[k], 4);
    float inv = 1.f / (den + 1e-16f);
#pragma unroll
    for (int k = 0; k < 12; ++k) acc[k] *= inv;

    // partial projection: K rows 12-23
    float zz[15];
#pragma unroll
    for (int cc = 0; cc < 15; ++cc) {
        int c = half * 15 + cc;
        float v = 0.f;
#pragma unroll
        for (int k = 0; k < 12; ++k) v += acc[k] * W2[(12 + k) * 120 + h * 30 + c];
        v += __shfl_xor(v, 1);
        v += __shfl_xor(v, 2);
        zz[cc] = v;          // head-summed; half0: ch 0-14, half1: ch 15-29
    }
    float zhi[15];
#pragma unroll
    for (int cc = 0; cc < 15; ++cc) zhi[cc] = __shfl_xor(zz[cc], 4);

    if (o == 0) {
        float z[30];
#pragma unroll
        for (int cc = 0; cc < 15; ++cc) {
            float v0 = 0.25f * (zz[cc] + zA[(size_t)n * 30 + cc]) + b2[cc];
            float v1 = 0.25f * (zhi[cc] + zA[(size_t)n * 30 + 15 + cc]) + b2[15 + cc];
            z[cc]      = v0 > 0.f ? v0 : 0.f;
            z[15 + cc] = v1 > 0.f ? v1 : 0.f;
        }
        float m2[15];
#pragma unroll
        for (int j = 0; j < 15; ++j) {
            float v = fb1[j];
#pragma unroll
            for (int c = 0; c < 30; ++c) v += z[c] * fw1[c * 15 + j];
            m2[j] = v > 0.f ? v : 0.f;
        }
#pragma unroll
        for (int k = 0; k < 2; ++k) {
            float v = fb2[k];
#pragma unroll
            for (int j = 0; j < 15; ++j) v += m2[j] * fw2[j * 2 + k];
            out[(size_t)n * 2 + k] = v;
        }
    }
}

// ===========================================================================
extern "C" void kernel_launch(void* const* d_in, const int* in_sizes, int n_in,
                              void* d_out, int out_size, void* d_ws, size_t ws_size,
                              hipStream_t stream)
{
    const float* x    = (const float*)d_in[0];
    const int*   ei   = (const int*)  d_in[1];
    // d_in[2] = edge_attr (ignored)
    const float* w1   = (const float*)d_in[3];
    const float* as1w = (const float*)d_in[4];
    const float* ad1w = (const float*)d_in[5];
    const float* b1   = (const float*)d_in[6];
    const float* w2   = (const float*)d_in[7];
    const float* as2w = (const float*)d_in[8];
    const float* ad2w = (const float*)d_in[9];
    const float* b2   = (const float*)d_in[10];
    const float* fw1  = (const float*)d_in[11];
    const float* fb1  = (const float*)d_in[12];
    const float* fw2  = (const float*)d_in[13];
    const float* fb2  = (const float*)d_in[14];

    const int N = in_sizes[0] / 6;
    const int E = in_sizes[1] / 2;
    const int* src = ei;
    const int* dst = ei + E;
    const int nbuck = (N + NPB - 1) / NPB;     // <= 1024 for N <= 131072

    float* ws = (float*)d_ws;
    size_t off = 0;
    float* row1 = ws + off; off += (size_t)N * 8;   // 32B rows (16B-aligned)
    float* rowA = ws + off; off += (size_t)N * 8;
    float* rowB = ws + off; off += (size_t)N * 8;
    float* ad1  = ws + off; off += (size_t)N * 4;
    float* ad2  = ws + off; off += (size_t)N * 4;
    float* zA   = ws + off; off += (size_t)N * 30;
    float* fold = ws + off; off += 256;

    int* iw = (int*)(ws + off);
    size_t ioff = 0;
    int* bcnt  = iw + ioff; ioff += MAXB;      // zeroed each call
    int* bbase = iw + ioff; ioff += MAXB;
    int* bcur  = iw + ioff; ioff += MAXB;
    int* rowp  = iw + ioff; ioff += N;
    int* deg   = iw + ioff; ioff += N;
    int* ebuf  = iw + ioff; ioff += E;         // packed, bucket-grouped
    int* esrc  = iw + ioff; ioff += E;         // per-node CSR order

    hipMemsetAsync(bcnt, 0, MAXB * sizeof(int), stream);

    const int B = 256;
    const int NB = (N + B - 1) / B;
    const int TB = (E + 4095) / 4096;
    const int OB = ((size_t)N * 8 + B - 1) / B;

    k_fold    <<<1, 256, 0, stream>>>(w1, as1w, ad1w, w2, as2w, ad2w, fold);

    // CSR build: bucket + within-bucket counting sort
    p0_count  <<<TB, B, 0, stream>>>(dst, bcnt, E, nbuck);
    p1_scan   <<<1, MAXB, 0, stream>>>(bcnt, bbase, bcur, nbuck);
    p2_scatter<<<TB, B, 0, stream>>>(src, dst, bcur, ebuf, E, nbuck);
    p3_sort   <<<nbuck, B, 0, stream>>>(bbase, bcnt, ebuf, rowp, deg, esrc, N);

    // layer 1
    k1_row    <<<NB, B, 0, stream>>>(x, fold, row1, ad1, N);
    k_gather1 <<<OB, B, 0, stream>>>(rowp, deg, esrc, row1, ad1, w1, b1, fold,
                                     rowA, rowB, ad2, N);

    // layer 2: two L2-resident channel passes
    k_g2a     <<<OB, B, 0, stream>>>(rowp, deg, esrc, rowA, ad2, w2, zA, N);
    k_g2b     <<<OB, B, 0, stream>>>(rowp, deg, esrc, rowB, ad2, w2, zA, b2,
                                     fw1, fb1, fw2, fb2, (float*)d_out, N);
}